// Round 11
// baseline (148.172 us; speedup 1.0000x reference)
//
#include <hip/hip_runtime.h>
#include <math.h>

// Problem constants (fixed by reference):
// B=4, N=2048, D=512, H=4, LH=AH=64, T=6400, lengths {2048,1536,1024,1792} (all %64==0)
// hb (bf16, 768 cols): v[0:256) DEAD/unwritten, q[256:512), k[512:768), head hd at +hd*64
// vtb (bf16): [d][token] V pre-transposed, written by k2's epilogue
// 5-kernel graph = the proven skeleton. History:
// R15: k1 wave-per-row. R16 FAILED: 128^2 undersubscribed. R17 (+3us): gload_lds +
//      XOR swizzle. R20 (+7.7us): k3 XCD->batch affinity + nt-streaming + k4a waverow.
// R21 FAILED: chunk=8 undersubscription (rule: blocks vs slots per domain).
// R22 (147.6): chunk=4 + k2 LDS-overlay epilogue. R23 (146.7): k3 gload_lds (-0.9).
// R24 (146.3): bn-pairing + XCD bm-swizzle (-0.4; k2 near structural cost).
// R25 (146.8, neutral): part/u -> bf16. No speed delta -> streaming traffic was not
//      critical-path. Kept (same absmax, less footprint). Lesson: traffic cuts don't
//      pay here; exposed latency might.
// R26: minimum-2-phase prefetch (T3-lite) in k2+k4b: issue tile t+1's gload_lds DMAs
//      BEFORE computing tile t (double-buffered LDS, ONE barrier/iter). The implicit
//      vmcnt(0) at the barrier then waits for loads aged by a full compute phase ->
//      exposed drain ~0, barriers halved. k2: 48KB dbuf -> 3 blocks/CU (800 blocks vs
//      768 slots = 1.04, OK). k4b: 32KB -> 5 blocks/CU. k3 unchanged (dbuf would cost
//      occupancy 5->3; separate experiment).

typedef __attribute__((ext_vector_type(8))) short bf16x8;   // 8 bf16 in 4 VGPRs
typedef __attribute__((ext_vector_type(4))) float f32x4;
typedef __attribute__((ext_vector_type(2))) unsigned int u32x2;
typedef __attribute__((ext_vector_type(4))) unsigned int u32x4;

__device__ __forceinline__ float silu_over_2048(float v) {
    return v * __builtin_amdgcn_rcpf(2048.0f + 2048.0f * __expf(-v));
}

__device__ __forceinline__ float silu_f(float v) {
    return v * __builtin_amdgcn_rcpf(1.0f + __expf(-v));
}

__device__ __forceinline__ unsigned short f2bf(float f) {  // RNE float->bf16
    unsigned int u = __float_as_uint(f);
    u += 0x7fffu + ((u >> 16) & 1u);
    return (unsigned short)(u >> 16);
}

__device__ __forceinline__ unsigned int f2bf2(float lo, float hi) {
#if __has_builtin(__builtin_amdgcn_cvt_pk_bf16_f32)
    typedef __attribute__((ext_vector_type(2))) short bf16x2;
    bf16x2 p = __builtin_amdgcn_cvt_pk_bf16_f32(lo, hi);
    return *(unsigned int*)&p;
#else
    return (unsigned int)f2bf(lo) | ((unsigned int)f2bf(hi) << 16);
#endif
}

// async global->LDS, 16B per lane. LDS dest is wave-uniform base + lane*16 (m104/m108):
// pass the SAME lds pointer for all lanes of a wave; per-lane global addresses.
__device__ __forceinline__ void gload_lds16(const unsigned short* g, unsigned short* l) {
    __builtin_amdgcn_global_load_lds(
        (const __attribute__((address_space(1))) void*)(g),
        (__attribute__((address_space(3))) void*)(l),
        16, 0, 0);
}

// ---------------- K1: LN one-wave-per-row (blocks 0..1599, 4 rows each) +
//                  uvqkT transpose (1600..1727) + owb cast (1728..1791) ----------------
__global__ __launch_bounds__(256) void k1_ln_prep(const float* __restrict__ x,
                                                  unsigned short* __restrict__ xnb,
                                                  const float* __restrict__ uvqk,
                                                  unsigned short* __restrict__ uvqkT,
                                                  const float* __restrict__ ow,
                                                  unsigned short* __restrict__ owb) {
    const int tid = threadIdx.x;
    const int bx = blockIdx.x;
    if (bx < 1600) {
        // one wave per row: lane handles 8 contiguous floats; wave-shuffle reduction only
        const int row = bx * 4 + (tid >> 6);
        const int lane = tid & 63;
        const float* xr = x + row * 512 + lane * 8;
        const float4 v0 = *(const float4*)xr;
        const float4 v1 = *(const float4*)(xr + 4);
        float s = v0.x + v0.y + v0.z + v0.w + v1.x + v1.y + v1.z + v1.w;
        float ss = v0.x * v0.x + v0.y * v0.y + v0.z * v0.z + v0.w * v0.w +
                   v1.x * v1.x + v1.y * v1.y + v1.z * v1.z + v1.w * v1.w;
#pragma unroll
        for (int off = 32; off > 0; off >>= 1) {
            s += __shfl_down(s, off);
            ss += __shfl_down(ss, off);
        }
        s = __shfl(s, 0);
        ss = __shfl(ss, 0);
        const float mean = s * (1.0f / 512.0f);
        const float var = ss * (1.0f / 512.0f) - mean * mean;  // biased, matches jnp.var
        const float rstd = rsqrtf(var + 1e-6f);
        unsigned int pk[4];
        pk[0] = f2bf2((v0.x - mean) * rstd, (v0.y - mean) * rstd);
        pk[1] = f2bf2((v0.z - mean) * rstd, (v0.w - mean) * rstd);
        pk[2] = f2bf2((v1.x - mean) * rstd, (v1.y - mean) * rstd);
        pk[3] = f2bf2((v1.z - mean) * rstd, (v1.w - mean) * rstd);
        *(uint4*)(xnb + row * 512 + lane * 8) = *(const uint4*)pk;
    } else if (bx < 1728) {
        __shared__ float L[64][68];
        const int t = bx - 1600;
        const int n0 = (t & 15) * 64;
        const int k0 = (t >> 4) * 64;
#pragma unroll
        for (int i = 0; i < 4; ++i) {
            const int r = (tid >> 4) + i * 16;
            const int c = (tid & 15) * 4;
            *(float4*)&L[r][c] = *(const float4*)(uvqk + (k0 + r) * 1024 + n0 + c);
        }
        __syncthreads();
        const int n = tid >> 2;
        const int kb = (tid & 3) * 16;
#pragma unroll
        for (int pass = 0; pass < 2; ++pass) {
            unsigned short pk[8];
#pragma unroll
            for (int j = 0; j < 8; ++j) pk[j] = f2bf(L[kb + pass * 8 + j][n]);
            *(uint4*)(uvqkT + (n0 + n) * 512 + k0 + kb + pass * 8) = *(const uint4*)pk;
        }
    } else {
        const int base = ((bx - 1728) * 256 + tid) * 8;
        float4 a = *(const float4*)(ow + base);
        float4 b = *(const float4*)(ow + base + 4);
        unsigned short pk[8] = {f2bf(a.x), f2bf(a.y), f2bf(a.z), f2bf(a.w),
                                f2bf(b.x), f2bf(b.y), f2bf(b.z), f2bf(b.w)};
        *(uint4*)(owb + base) = *(const uint4*)pk;
    }
}

// ---------------- K2: h = silu(xn @ uvqk); u -> bf16, q/k -> hb bf16, v -> vtb bf16 (transposed)
//                  64-row A-tile x TWO 64-col B-tiles (bn-pair), gload_lds + XOR swizzle,
//                  XCD bm-chunk swizzle, 2-phase double-buffered prefetch ----------------
__global__ __launch_bounds__(256, 3) void k2_gemm1(const unsigned short* __restrict__ A,
                                                   const unsigned short* __restrict__ Bt,
                                                   unsigned short* __restrict__ u_out,
                                                   unsigned short* __restrict__ hb,
                                                   unsigned short* __restrict__ vtb) {
    __shared__ __align__(16) unsigned short smem[24576];  // 2 x (As|Bs0|Bs1), 48 KB dbuf
    const int tid = threadIdx.x;
    const int lane = tid & 63;
    const int w = tid >> 6;
    const int l15 = lane & 15;
    const int quad = lane >> 4;
    // XCD bm-chunk swizzle: nwg=800, xcd = bid%8 gets contiguous k-range -> contiguous bm.
    const int bid = blockIdx.x;
    const int kk_ = (bid & 7) * 100 + (bid >> 3);
    const int bm = (kk_ >> 3) * 64;
    const int bn0 = (kk_ & 7) * 128;  // pair: bn0, bn0+64 (128-aligned -> same region)

    const int srow = lane >> 3;                      // 0..7
    const int scol = ((lane & 7) ^ srow) * 8;        // pre-swizzled col (shorts)
    const unsigned short* gA = A + (size_t)(bm + w * 8 + srow) * 512 + scol;
    const unsigned short* gB0 = Bt + (size_t)(bn0 + w * 8 + srow) * 512 + scol;
    const unsigned short* gB1 = Bt + (size_t)(bn0 + 64 + w * 8 + srow) * 512 + scol;

    auto stage = [&](int kc, unsigned short* base) {
#pragma unroll
        for (int i = 0; i < 2; ++i) {
            gload_lds16(gA + (size_t)(i * 32) * 512 + kc, base + (w + i * 4) * 512);
            gload_lds16(gB0 + (size_t)(i * 32) * 512 + kc, base + 4096 + (w + i * 4) * 512);
            gload_lds16(gB1 + (size_t)(i * 32) * 512 + kc, base + 8192 + (w + i * 4) * 512);
        }
    };

    const int xA = (l15 & 7) << 3;  // read-side XOR; frag rows are *16 + l15
    f32x4 acc[2][4] = {};
    stage(0, smem);
    __syncthreads();  // tile 0 ready
#pragma unroll
    for (int it = 0; it < 8; ++it) {
        unsigned short* cb = smem + (it & 1) * 12288;
        if (it < 7) stage((it + 1) * 64, smem + ((it + 1) & 1) * 12288);  // prefetch t+1
        const unsigned short* Bs0 = cb + 4096;
        const unsigned short* Bs1 = cb + 8192;
        const bf16x8 a0 = *(const bf16x8*)&cb[(w * 16 + l15) * 64 + ((quad * 8) ^ xA)];
        const bf16x8 a1 = *(const bf16x8*)&cb[(w * 16 + l15) * 64 + ((32 + quad * 8) ^ xA)];
#pragma unroll
        for (int nt = 0; nt < 4; ++nt) {
            bf16x8 b0 = *(const bf16x8*)&Bs0[(nt * 16 + l15) * 64 + ((quad * 8) ^ xA)];
            bf16x8 b1 = *(const bf16x8*)&Bs0[(nt * 16 + l15) * 64 + ((32 + quad * 8) ^ xA)];
            acc[0][nt] = __builtin_amdgcn_mfma_f32_16x16x32_bf16(a0, b0, acc[0][nt], 0, 0, 0);
            acc[0][nt] = __builtin_amdgcn_mfma_f32_16x16x32_bf16(a1, b1, acc[0][nt], 0, 0, 0);
        }
#pragma unroll
        for (int nt = 0; nt < 4; ++nt) {
            bf16x8 b0 = *(const bf16x8*)&Bs1[(nt * 16 + l15) * 64 + ((quad * 8) ^ xA)];
            bf16x8 b1 = *(const bf16x8*)&Bs1[(nt * 16 + l15) * 64 + ((32 + quad * 8) ^ xA)];
            acc[1][nt] = __builtin_amdgcn_mfma_f32_16x16x32_bf16(a0, b0, acc[1][nt], 0, 0, 0);
            acc[1][nt] = __builtin_amdgcn_mfma_f32_16x16x32_bf16(a1, b1, acc[1][nt], 0, 0, 0);
        }
        __syncthreads();  // drains aged t+1 DMAs; guards buffer reuse. ONE barrier/iter.
    }
    const int m = bm + w * 16 + quad * 4;
    unsigned short(*T)[72] = (unsigned short(*)[72])smem;  // 64x72 = 9216 B overlay
    if (bn0 < 256) {  // u region -> bf16 via row-major LDS overlay, nt uint4 stores
#pragma unroll
        for (int p = 0; p < 2; ++p) {
            __syncthreads();  // waves done with prior T use
#pragma unroll
            for (int nt = 0; nt < 4; ++nt) {
                unsigned int p01 = f2bf2(silu_f(acc[p][nt][0]), silu_f(acc[p][nt][1]));
                unsigned int p23 = f2bf2(silu_f(acc[p][nt][2]), silu_f(acc[p][nt][3]));
                T[w * 16 + quad * 4 + 0][nt * 16 + l15] = (unsigned short)p01;
                T[w * 16 + quad * 4 + 1][nt * 16 + l15] = (unsigned short)(p01 >> 16);
                T[w * 16 + quad * 4 + 2][nt * 16 + l15] = (unsigned short)p23;
                T[w * 16 + quad * 4 + 3][nt * 16 + l15] = (unsigned short)(p23 >> 16);
            }
            __syncthreads();
            const int sr = tid >> 3, sc2 = (tid & 7) * 8;
#pragma unroll
            for (int i = 0; i < 2; ++i) {
                const int r = sr + i * 32;
                __builtin_nontemporal_store(
                    *(const u32x4*)&T[r][sc2],
                    (u32x4*)(u_out + (size_t)(bm + r) * 256 + bn0 + p * 64 + sc2));
            }
        }
    } else if (bn0 < 512) {  // v region -> vtb (transposed) via padded-LDS overlay, per pair
#pragma unroll
        for (int p = 0; p < 2; ++p) {
            __syncthreads();
#pragma unroll
            for (int nt = 0; nt < 4; ++nt) {
                unsigned int p01 = f2bf2(silu_f(acc[p][nt][0]), silu_f(acc[p][nt][1]));
                unsigned int p23 = f2bf2(silu_f(acc[p][nt][2]), silu_f(acc[p][nt][3]));
                unsigned int pk2[2] = {p01, p23};
                *(uint2*)&T[nt * 16 + l15][w * 16 + quad * 4] = *(const uint2*)pk2;
            }
            __syncthreads();
            const int sr = tid >> 3, sc2 = (tid & 7) * 8;
#pragma unroll
            for (int i = 0; i < 2; ++i) {
                const int r = sr + i * 32;
                *(uint4*)(vtb + (size_t)(bn0 - 256 + p * 64 + r) * 6400 + bm + sc2) =
                    *(const uint4*)&T[r][sc2];
            }
        }
    } else {  // q/k region -> hb via row-major LDS overlay, coalesced uint4 stores, per pair
#pragma unroll
        for (int p = 0; p < 2; ++p) {
            __syncthreads();
#pragma unroll
            for (int nt = 0; nt < 4; ++nt) {
                unsigned int p01 = f2bf2(silu_f(acc[p][nt][0]), silu_f(acc[p][nt][1]));
                unsigned int p23 = f2bf2(silu_f(acc[p][nt][2]), silu_f(acc[p][nt][3]));
                T[w * 16 + quad * 4 + 0][nt * 16 + l15] = (unsigned short)p01;
                T[w * 16 + quad * 4 + 1][nt * 16 + l15] = (unsigned short)(p01 >> 16);
                T[w * 16 + quad * 4 + 2][nt * 16 + l15] = (unsigned short)p23;
                T[w * 16 + quad * 4 + 3][nt * 16 + l15] = (unsigned short)(p23 >> 16);
            }
            __syncthreads();
            const int sr = tid >> 3, sc2 = (tid & 7) * 8;
#pragma unroll
            for (int i = 0; i < 2; ++i) {
                const int r = sr + i * 32;
                *(uint4*)(hb + (size_t)(bm + r) * 768 + (bn0 - 256) + p * 64 + sc2) =
                    *(const uint4*)&T[r][sc2];
            }
        }
    }
}

// ---------------- K3: fused jagged SiLU attention, split-K (chunk=4), XCD->batch affinity,
//                  K/V staged via gload_lds into XOR-swizzled linear LDS; part -> bf16 --------
__global__ __launch_bounds__(256, 5) void k3_attn(const unsigned short* __restrict__ hb,
                                                  const unsigned short* __restrict__ vtb,
                                                  const int* __restrict__ ts,
                                                  const float* __restrict__ tsw,
                                                  const int* __restrict__ offs,
                                                  unsigned short* __restrict__ part) {
    // XCD-affinity decode (assumes xcd = linear_bid % 8; wrong assumption -> only mixes
    // batches, never wrong results). Work shares {3,2,1,2} XCDs for b={0,1,2,3}.
    // 32 slots per qt (8 chunks x 4 heads); per-XCD stream r = slot*kx + xi, qt
    // descending = LPT. Capacity: nqt*32 <= 512*kx holds for all b at these lengths.
    const int xcd = blockIdx.x & 7;
    const int slot = blockIdx.x >> 3;
    const int b = (xcd < 3) ? 0 : (xcd < 5) ? 1 : (xcd == 5) ? 2 : 3;
    const int xst = (b == 0) ? 0 : (b == 1) ? 3 : (b == 2) ? 5 : 6;
    const int kx = (b == 0) ? 3 : (b == 2) ? 1 : 2;
    const int r = slot * kx + (xcd - xst);
    const int off = offs[b];
    const int len = offs[b + 1] - off;
    const int nqt = len >> 6;
    const int qt_lpt = r >> 5;
    if (qt_lpt >= nqt) return;
    const int qt = nqt - 1 - qt_lpt;
    const int c = (r >> 2) & 7;
    const int hd = r & 3;
    if (c * 4 > qt) return;
    const int q0 = qt * 64;
    const int kt_lo = c * 4;
    const int kt_hi = min(qt, c * 4 + 3);

    __shared__ __align__(16) unsigned short QPs[64][72];  // Qs during init, Ps in loop (padded)
    __shared__ __align__(16) unsigned short Ks[4096];     // linear [64][64], XOR-swizzled
    __shared__ __align__(16) unsigned short Vt[4096];     // linear [64][64], XOR-swizzled
    __shared__ float tqf[64], tkf[64];
    __shared__ float tw[132];

    const int tid = threadIdx.x;
    const int lane = tid & 63;
    const int w = tid >> 6;
    const int l15 = lane & 15;
    const int quad = lane >> 4;
    const int sr = tid >> 3;
    const int sc = (tid & 7) * 8;

    // gload_lds staging geometry (same as k2): chunk j covers rows j*8..j*8+7;
    // lane l -> row (l>>3), col-group (l&7); pre-swizzled global col.
    const int srow = lane >> 3;
    const int scol = ((lane & 7) ^ srow) * 8;
    const int xA = (l15 & 7) << 3;  // read-side XOR

    if (tid < 129) tw[tid] = tsw[tid];
    if (tid < 64) tqf[tid] = (float)ts[b * 2048 + q0 + tid];
#pragma unroll
    for (int i = 0; i < 2; ++i)
        *(uint4*)&QPs[sr + i * 32][sc] =
            *(const uint4*)(hb + (off + q0 + sr + i * 32) * 768 + 256 + hd * 64 + sc);
    __syncthreads();

    const bf16x8 aQ0 = *(const bf16x8*)&QPs[w * 16 + l15][quad * 8];
    const bf16x8 aQ1 = *(const bf16x8*)&QPs[w * 16 + l15][32 + quad * 8];
    const f32x4 tq4 = *(const f32x4*)&tqf[w * 16 + quad * 4];
    const int nbase = q0 + w * 16 + quad * 4;

    // per-lane global staging bases (row offsets added per kt)
    const unsigned short* gK = hb + (size_t)(off + w * 8 + srow) * 768 + 512 + hd * 64 + scol;
    const unsigned short* gV = vtb + (size_t)(hd * 64 + w * 8 + srow) * 6400 + off + scol;

    f32x4 oacc[4] = {};

    for (int kt = kt_lo; kt <= kt_hi; ++kt) {
        const int m0 = kt * 64;
        __syncthreads();  // prior iteration's Ks/Vt/Ps reads done
#pragma unroll
        for (int i = 0; i < 2; ++i) {
            gload_lds16(gK + (size_t)(m0 + i * 32) * 768, Ks + (w + i * 4) * 512);
            gload_lds16(gV + (size_t)(i * 32) * 6400 + m0, Vt + (w + i * 4) * 512);
        }
        if (tid < 64) tkf[tid] = (float)ts[b * 2048 + m0 + tid];
        __syncthreads();  // vmcnt+lgkm drain -> tiles ready

        // S = Q @ K^T
        f32x4 s[4] = {};
#pragma unroll
        for (int nt = 0; nt < 4; ++nt) {
            bf16x8 b0 = *(const bf16x8*)&Ks[(nt * 16 + l15) * 64 + ((quad * 8) ^ xA)];
            bf16x8 b1 = *(const bf16x8*)&Ks[(nt * 16 + l15) * 64 + ((32 + quad * 8) ^ xA)];
            s[nt] = __builtin_amdgcn_mfma_f32_16x16x32_bf16(aQ0, b0, s[nt], 0, 0, 0);
            s[nt] = __builtin_amdgcn_mfma_f32_16x16x32_bf16(aQ1, b1, s[nt], 0, 0, 0);
        }

        // bias + silu/N + diagonal mask -> Ps (packed bf16 conversion)
        const bool diag = (kt == qt);
#pragma unroll
        for (int nt = 0; nt < 4; ++nt) {
            const int m = m0 + nt * 16 + l15;
            const float tk = tkf[nt * 16 + l15];
            float p[4];
#pragma unroll
            for (int reg = 0; reg < 4; ++reg) {
                const float delta = fabsf(tq4[reg] - tk);
                const int bucket = (int)(__log2f(1.0f + delta) * 0.6931471805599453f);
                float val = s[nt][reg] + tw[bucket];
                float pv = silu_over_2048(val);
                if (diag) pv = (m <= nbase + reg) ? pv : 0.0f;
                p[reg] = pv;
            }
            const unsigned int p01 = f2bf2(p[0], p[1]);
            const unsigned int p23 = f2bf2(p[2], p[3]);
            QPs[w * 16 + quad * 4 + 0][nt * 16 + l15] = (unsigned short)p01;
            QPs[w * 16 + quad * 4 + 1][nt * 16 + l15] = (unsigned short)(p01 >> 16);
            QPs[w * 16 + quad * 4 + 2][nt * 16 + l15] = (unsigned short)p23;
            QPs[w * 16 + quad * 4 + 3][nt * 16 + l15] = (unsigned short)(p23 >> 16);
        }
        // wave reads back only its own Ps rows -> no barrier needed

        const bf16x8 aP0 = *(const bf16x8*)&QPs[w * 16 + l15][quad * 8];
        const bf16x8 aP1 = *(const bf16x8*)&QPs[w * 16 + l15][32 + quad * 8];
#pragma unroll
        for (int nt = 0; nt < 4; ++nt) {
            bf16x8 v0 = *(const bf16x8*)&Vt[(nt * 16 + l15) * 64 + ((quad * 8) ^ xA)];
            bf16x8 v1 = *(const bf16x8*)&Vt[(nt * 16 + l15) * 64 + ((32 + quad * 8) ^ xA)];
            oacc[nt] = __builtin_amdgcn_mfma_f32_16x16x32_bf16(aP0, v0, oacc[nt], 0, 0, 0);
            oacc[nt] = __builtin_amdgcn_mfma_f32_16x16x32_bf16(aP1, v1, oacc[nt], 0, 0, 0);
        }
    }

    // part is streaming (read once by k4a): bf16 + nontemporal, keep K/V resident in L2
    unsigned short* pc = part + (size_t)c * (6400 * 256);
#pragma unroll
    for (int nt = 0; nt < 4; ++nt)
#pragma unroll
        for (int reg = 0; reg < 4; ++reg)
            __builtin_nontemporal_store(
                f2bf(oacc[nt][reg]),
                &pc[(off + q0 + w * 16 + quad * 4 + reg) * 256 + hd * 64 + nt * 16 + l15]);
}

// ---------------- K4a: o_in = bf16(u * layernorm(sum_c part[c])); one wave per row;
//                  part/u read as bf16 (shift-unpack) ----------------
__global__ __launch_bounds__(256) void k4a_ln(const unsigned short* __restrict__ part,
                                              const unsigned short* __restrict__ u_in,
                                              const int* __restrict__ token_pos,
                                              unsigned short* __restrict__ o_in) {
    const int row = blockIdx.x * 4 + (threadIdx.x >> 6);
    const int lane = threadIdx.x & 63;
    const int qt = token_pos[row] >> 6;
    const int nch = (qt + 4) >> 2;  // ceil((qt+1)/4), max 8
    const size_t base = (size_t)row * 256 + lane * 4;
    float a0 = 0.0f, a1 = 0.0f, a2 = 0.0f, a3 = 0.0f;
    for (int cc = 0; cc < nch; ++cc) {
        const u32x2 pw =
            __builtin_nontemporal_load((const u32x2*)(part + (size_t)cc * (6400 * 256) + base));
        a0 += __uint_as_float(pw[0] << 16);
        a1 += __uint_as_float(pw[0] & 0xffff0000u);
        a2 += __uint_as_float(pw[1] << 16);
        a3 += __uint_as_float(pw[1] & 0xffff0000u);
    }
    float s = a0 + a1 + a2 + a3;
    float ss = a0 * a0 + a1 * a1 + a2 * a2 + a3 * a3;
#pragma unroll
    for (int off = 32; off > 0; off >>= 1) {
        s += __shfl_down(s, off);
        ss += __shfl_down(ss, off);
    }
    s = __shfl(s, 0);
    ss = __shfl(ss, 0);
    const float mean = s * (1.0f / 256.0f);
    const float var = ss * (1.0f / 256.0f) - mean * mean;
    const float rstd = rsqrtf(var + 1e-6f);
    const u32x2 uw = __builtin_nontemporal_load((const u32x2*)(u_in + base));
    const float u0 = __uint_as_float(uw[0] << 16);
    const float u1 = __uint_as_float(uw[0] & 0xffff0000u);
    const float u2 = __uint_as_float(uw[1] << 16);
    const float u3 = __uint_as_float(uw[1] & 0xffff0000u);
    unsigned int pk[2];
    pk[0] = f2bf2(u0 * (a0 - mean) * rstd, u1 * (a1 - mean) * rstd);
    pk[1] = f2bf2(u2 * (a2 - mean) * rstd, u3 * (a3 - mean) * rstd);
    *(uint2*)(o_in + base) = *(const uint2*)pk;
}

// ---------------- K4b: out = o_in @ o_w^T + o_b + x via bf16 MFMA
//                  64x64 tile, gload_lds + XOR swizzle, XCD bm-chunk swizzle,
//                  2-phase double-buffered prefetch ----------------
__global__ __launch_bounds__(256, 4) void k4b_gemm2(const unsigned short* __restrict__ A,
                                                    const unsigned short* __restrict__ owb,
                                                    const float* __restrict__ ob,
                                                    const float* __restrict__ x,
                                                    float* __restrict__ out) {
    __shared__ __align__(16) unsigned short smem[16384];  // 2 x (As|Bs), 32 KB dbuf
    const int tid = threadIdx.x;
    const int lane = tid & 63;
    const int w = tid >> 6;
    const int l15 = lane & 15;
    const int quad = lane >> 4;
    // XCD bm-chunk swizzle: nwg=800 (%8==0 -> bijective)
    const int bid = blockIdx.x;
    const int kk_ = (bid & 7) * 100 + (bid >> 3);
    const int bm = (kk_ >> 3) * 64;
    const int bn = (kk_ & 7) * 64;

    const int srow = lane >> 3;
    const int scol = ((lane & 7) ^ srow) * 8;
    const unsigned short* gA = A + (size_t)(bm + w * 8 + srow) * 256 + scol;
    const unsigned short* gB = owb + (size_t)(bn + w * 8 + srow) * 256 + scol;

    auto stage = [&](int kc, unsigned short* base) {
#pragma unroll
        for (int i = 0; i < 2; ++i) {
            gload_lds16(gA + (size_t)(i * 32) * 256 + kc, base + (w + i * 4) * 512);
            gload_lds16(gB + (size_t)(i * 32) * 256 + kc, base + 4096 + (w + i * 4) * 512);
        }
    };

    const int xA = (l15 & 7) << 3;
    f32x4 acc[4] = {};
    stage(0, smem);
    __syncthreads();  // tile 0 ready
#pragma unroll
    for (int it = 0; it < 4; ++it) {
        unsigned short* cb = smem + (it & 1) * 8192;
        if (it < 3) stage((it + 1) * 64, smem + ((it + 1) & 1) * 8192);  // prefetch t+1
        const unsigned short* Bs = cb + 4096;
        const bf16x8 a0 = *(const bf16x8*)&cb[(w * 16 + l15) * 64 + ((quad * 8) ^ xA)];
        const bf16x8 a1 = *(const bf16x8*)&cb[(w * 16 + l15) * 64 + ((32 + quad * 8) ^ xA)];
#pragma unroll
        for (int nt = 0; nt < 4; ++nt) {
            bf16x8 b0 = *(const bf16x8*)&Bs[(nt * 16 + l15) * 64 + ((quad * 8) ^ xA)];
            bf16x8 b1 = *(const bf16x8*)&Bs[(nt * 16 + l15) * 64 + ((32 + quad * 8) ^ xA)];
            acc[nt] = __builtin_amdgcn_mfma_f32_16x16x32_bf16(a0, b0, acc[nt], 0, 0, 0);
            acc[nt] = __builtin_amdgcn_mfma_f32_16x16x32_bf16(a1, b1, acc[nt], 0, 0, 0);
        }
        __syncthreads();  // drains aged t+1 DMAs; guards buffer reuse
    }
    const int m = bm + w * 16 + quad * 4;
#pragma unroll
    for (int nt = 0; nt < 4; ++nt) {
        const int d = bn + nt * 16 + l15;
        const float bias = ob[d];
#pragma unroll
        for (int reg = 0; reg < 4; ++reg)
            out[(m + reg) * 512 + d] = acc[nt][reg] + bias + x[(m + reg) * 512 + d];
    }
}

extern "C" void kernel_launch(void* const* d_in, const int* in_sizes, int n_in,
                              void* d_out, int out_size, void* d_ws, size_t ws_size,
                              hipStream_t stream) {
    const float* x = (const float*)d_in[0];       // [6400,512]
    const float* uvqk = (const float*)d_in[1];    // [512,1024]
    const float* ow = (const float*)d_in[2];      // [512,256]
    const float* ob = (const float*)d_in[3];      // [512]
    const float* tsw = (const float*)d_in[4];     // [129]
    const int* ts = (const int*)d_in[5];          // [4,2048]
    // d_in[6] invalid_attn_mask: pure tril -> implemented as m<=n, not read
    const int* offs = (const int*)d_in[7];        // [5]
    // d_in[8] token_batch (unused)
    const int* token_pos = (const int*)d_in[9];   // [6400]
    float* out = (float*)d_out;                   // [6400,512]

    unsigned short* u = (unsigned short*)d_ws;    // 6400*256 bf16
    unsigned short* part = u + 6400 * 256;        // 8*6400*256 bf16 (split-K partials)
    unsigned short* xnb = part + 8 * 6400 * 256;  // 6400*512 bf16
    unsigned short* hb = xnb + 6400 * 512;        // 6400*768 bf16 (v cols unwritten)
    unsigned short* o_in = hb + 6400 * 768;       // 6400*256 bf16
    unsigned short* uvqkT = o_in + 6400 * 256;    // 1024*512 bf16
    unsigned short* owb = uvqkT + 1024 * 512;     // 512*256 bf16
    unsigned short* vtb = owb + 512 * 256;        // 256*6400 bf16
    // total ws use: ~55 MB

    k1_ln_prep<<<1792, 256, 0, stream>>>(x, xnb, uvqk, uvqkT, ow, owb);
    k2_gemm1<<<800, 256, 0, stream>>>(xnb, uvqkT, u, hb, vtb);
    k3_attn<<<4096, 256, 0, stream>>>(hb, vtb, ts, tsw, offs, part);
    k4a_ln<<<1600, 256, 0, stream>>>(part, u, token_pos, o_in);
    k4b_gemm2<<<800, 256, 0, stream>>>(o_in, owb, ob, x, out);
}

// Round 12
// 146.605 us; speedup vs baseline: 1.0107x; 1.0107x over previous
//
#include <hip/hip_runtime.h>
#include <math.h>

// Problem constants (fixed by reference):
// B=4, N=2048, D=512, H=4, LH=AH=64, T=6400, lengths {2048,1536,1024,1792} (all %64==0)
// hb (bf16, 768 cols): v[0:256) DEAD/unwritten, q[256:512), k[512:768), head hd at +hd*64
// vtb (bf16): [d][token] V pre-transposed, written by k2's epilogue
// 5-kernel graph = the proven skeleton. History:
// R15: k1 wave-per-row. R16 FAILED: 128^2 undersubscribed. R17 (+3us): gload_lds +
//      XOR swizzle. R20 (+7.7us): k3 XCD->batch affinity + nt-streaming + k4a waverow.
// R21 FAILED: chunk=8 undersubscription (rule: blocks vs slots per domain).
// R22 (147.6): chunk=4 + k2 LDS-overlay epilogue. R23 (146.7): k3 gload_lds (-0.9).
// R24 (146.3, BEST): bn-pairing + XCD bm-swizzle.
// R25 (146.8, neutral): part/u bf16 -- streaming traffic not critical-path.
// R26 FAILED (148.2): 2-phase dbuf cost occupancy (4->3 blocks/CU), gained nothing
//      (compiler's implicit wave-overlap already covers staging latency; m99/m100).
// R27: REVERT to exact R24 config (measured session best). Three lever classes
//      (interior tiling, streaming traffic, staging latency) all tested structural.

typedef __attribute__((ext_vector_type(8))) short bf16x8;   // 8 bf16 in 4 VGPRs
typedef __attribute__((ext_vector_type(4))) float f32x4;

__device__ __forceinline__ float silu_over_2048(float v) {
    return v * __builtin_amdgcn_rcpf(2048.0f + 2048.0f * __expf(-v));
}

__device__ __forceinline__ float silu_f(float v) {
    return v * __builtin_amdgcn_rcpf(1.0f + __expf(-v));
}

__device__ __forceinline__ unsigned short f2bf(float f) {  // RNE float->bf16
    unsigned int u = __float_as_uint(f);
    u += 0x7fffu + ((u >> 16) & 1u);
    return (unsigned short)(u >> 16);
}

__device__ __forceinline__ unsigned int f2bf2(float lo, float hi) {
#if __has_builtin(__builtin_amdgcn_cvt_pk_bf16_f32)
    typedef __attribute__((ext_vector_type(2))) short bf16x2;
    bf16x2 p = __builtin_amdgcn_cvt_pk_bf16_f32(lo, hi);
    return *(unsigned int*)&p;
#else
    return (unsigned int)f2bf(lo) | ((unsigned int)f2bf(hi) << 16);
#endif
}

// async global->LDS, 16B per lane. LDS dest is wave-uniform base + lane*16 (m104/m108):
// pass the SAME lds pointer for all lanes of a wave; per-lane global addresses.
__device__ __forceinline__ void gload_lds16(const unsigned short* g, unsigned short* l) {
    __builtin_amdgcn_global_load_lds(
        (const __attribute__((address_space(1))) void*)(g),
        (__attribute__((address_space(3))) void*)(l),
        16, 0, 0);
}

// ---------------- K1: LN one-wave-per-row (blocks 0..1599, 4 rows each) +
//                  uvqkT transpose (1600..1727) + owb cast (1728..1791) ----------------
__global__ __launch_bounds__(256) void k1_ln_prep(const float* __restrict__ x,
                                                  unsigned short* __restrict__ xnb,
                                                  const float* __restrict__ uvqk,
                                                  unsigned short* __restrict__ uvqkT,
                                                  const float* __restrict__ ow,
                                                  unsigned short* __restrict__ owb) {
    const int tid = threadIdx.x;
    const int bx = blockIdx.x;
    if (bx < 1600) {
        // one wave per row: lane handles 8 contiguous floats; wave-shuffle reduction only
        const int row = bx * 4 + (tid >> 6);
        const int lane = tid & 63;
        const float* xr = x + row * 512 + lane * 8;
        const float4 v0 = *(const float4*)xr;
        const float4 v1 = *(const float4*)(xr + 4);
        float s = v0.x + v0.y + v0.z + v0.w + v1.x + v1.y + v1.z + v1.w;
        float ss = v0.x * v0.x + v0.y * v0.y + v0.z * v0.z + v0.w * v0.w +
                   v1.x * v1.x + v1.y * v1.y + v1.z * v1.z + v1.w * v1.w;
#pragma unroll
        for (int off = 32; off > 0; off >>= 1) {
            s += __shfl_down(s, off);
            ss += __shfl_down(ss, off);
        }
        s = __shfl(s, 0);
        ss = __shfl(ss, 0);
        const float mean = s * (1.0f / 512.0f);
        const float var = ss * (1.0f / 512.0f) - mean * mean;  // biased, matches jnp.var
        const float rstd = rsqrtf(var + 1e-6f);
        unsigned int pk[4];
        pk[0] = f2bf2((v0.x - mean) * rstd, (v0.y - mean) * rstd);
        pk[1] = f2bf2((v0.z - mean) * rstd, (v0.w - mean) * rstd);
        pk[2] = f2bf2((v1.x - mean) * rstd, (v1.y - mean) * rstd);
        pk[3] = f2bf2((v1.z - mean) * rstd, (v1.w - mean) * rstd);
        *(uint4*)(xnb + row * 512 + lane * 8) = *(const uint4*)pk;
    } else if (bx < 1728) {
        __shared__ float L[64][68];
        const int t = bx - 1600;
        const int n0 = (t & 15) * 64;
        const int k0 = (t >> 4) * 64;
#pragma unroll
        for (int i = 0; i < 4; ++i) {
            const int r = (tid >> 4) + i * 16;
            const int c = (tid & 15) * 4;
            *(float4*)&L[r][c] = *(const float4*)(uvqk + (k0 + r) * 1024 + n0 + c);
        }
        __syncthreads();
        const int n = tid >> 2;
        const int kb = (tid & 3) * 16;
#pragma unroll
        for (int pass = 0; pass < 2; ++pass) {
            unsigned short pk[8];
#pragma unroll
            for (int j = 0; j < 8; ++j) pk[j] = f2bf(L[kb + pass * 8 + j][n]);
            *(uint4*)(uvqkT + (n0 + n) * 512 + k0 + kb + pass * 8) = *(const uint4*)pk;
        }
    } else {
        const int base = ((bx - 1728) * 256 + tid) * 8;
        float4 a = *(const float4*)(ow + base);
        float4 b = *(const float4*)(ow + base + 4);
        unsigned short pk[8] = {f2bf(a.x), f2bf(a.y), f2bf(a.z), f2bf(a.w),
                                f2bf(b.x), f2bf(b.y), f2bf(b.z), f2bf(b.w)};
        *(uint4*)(owb + base) = *(const uint4*)pk;
    }
}

// ---------------- K2: h = silu(xn @ uvqk); u -> fp32, q/k -> hb bf16, v -> vtb bf16 (transposed)
//                  64-row A-tile x TWO 64-col B-tiles (bn-pair), gload_lds + XOR swizzle,
//                  XCD bm-chunk swizzle ----------------
__global__ __launch_bounds__(256, 4) void k2_gemm1(const unsigned short* __restrict__ A,
                                                   const unsigned short* __restrict__ Bt,
                                                   float* __restrict__ u_out,
                                                   unsigned short* __restrict__ hb,
                                                   unsigned short* __restrict__ vtb) {
    __shared__ __align__(16) unsigned short smem[12288];  // As[64][64] | Bs0 | Bs1, 24 KB
    unsigned short* As = smem;   // element (r,c) at short-index r*64 + (c ^ ((r&7)<<3))
    unsigned short* Bs0 = smem + 4096;
    unsigned short* Bs1 = smem + 8192;
    const int tid = threadIdx.x;
    const int lane = tid & 63;
    const int w = tid >> 6;
    const int l15 = lane & 15;
    const int quad = lane >> 4;
    // XCD bm-chunk swizzle: nwg=800, xcd = bid%8 gets contiguous k-range -> contiguous bm.
    const int bid = blockIdx.x;
    const int kk_ = (bid & 7) * 100 + (bid >> 3);
    const int bm = (kk_ >> 3) * 64;
    const int bn0 = (kk_ & 7) * 128;  // pair: bn0, bn0+64 (128-aligned -> same region)

    const int srow = lane >> 3;                      // 0..7
    const int scol = ((lane & 7) ^ srow) * 8;        // pre-swizzled col (shorts)
    const unsigned short* gA = A + (size_t)(bm + w * 8 + srow) * 512 + scol;
    const unsigned short* gB0 = Bt + (size_t)(bn0 + w * 8 + srow) * 512 + scol;
    const unsigned short* gB1 = Bt + (size_t)(bn0 + 64 + w * 8 + srow) * 512 + scol;

    const int xA = (l15 & 7) << 3;  // read-side XOR; frag rows are *16 + l15
    f32x4 acc[2][4] = {};
    for (int kc = 0; kc < 512; kc += 64) {
        __syncthreads();  // prev iteration's LDS reads done
#pragma unroll
        for (int i = 0; i < 2; ++i) {
            gload_lds16(gA + (size_t)(i * 32) * 512 + kc, As + (w + i * 4) * 512);
            gload_lds16(gB0 + (size_t)(i * 32) * 512 + kc, Bs0 + (w + i * 4) * 512);
            gload_lds16(gB1 + (size_t)(i * 32) * 512 + kc, Bs1 + (w + i * 4) * 512);
        }
        __syncthreads();  // vmcnt(0) drain -> tiles ready
        const bf16x8 a0 = *(const bf16x8*)&As[(w * 16 + l15) * 64 + ((quad * 8) ^ xA)];
        const bf16x8 a1 = *(const bf16x8*)&As[(w * 16 + l15) * 64 + ((32 + quad * 8) ^ xA)];
#pragma unroll
        for (int nt = 0; nt < 4; ++nt) {
            bf16x8 b0 = *(const bf16x8*)&Bs0[(nt * 16 + l15) * 64 + ((quad * 8) ^ xA)];
            bf16x8 b1 = *(const bf16x8*)&Bs0[(nt * 16 + l15) * 64 + ((32 + quad * 8) ^ xA)];
            acc[0][nt] = __builtin_amdgcn_mfma_f32_16x16x32_bf16(a0, b0, acc[0][nt], 0, 0, 0);
            acc[0][nt] = __builtin_amdgcn_mfma_f32_16x16x32_bf16(a1, b1, acc[0][nt], 0, 0, 0);
        }
#pragma unroll
        for (int nt = 0; nt < 4; ++nt) {
            bf16x8 b0 = *(const bf16x8*)&Bs1[(nt * 16 + l15) * 64 + ((quad * 8) ^ xA)];
            bf16x8 b1 = *(const bf16x8*)&Bs1[(nt * 16 + l15) * 64 + ((32 + quad * 8) ^ xA)];
            acc[1][nt] = __builtin_amdgcn_mfma_f32_16x16x32_bf16(a0, b0, acc[1][nt], 0, 0, 0);
            acc[1][nt] = __builtin_amdgcn_mfma_f32_16x16x32_bf16(a1, b1, acc[1][nt], 0, 0, 0);
        }
    }
    const int m = bm + w * 16 + quad * 4;
    unsigned short(*T)[72] = (unsigned short(*)[72])smem;  // 64x72 = 9216 B overlay
    if (bn0 < 256) {  // u region -> fp32, nontemporal (single-use by k4a)
#pragma unroll
        for (int p = 0; p < 2; ++p)
#pragma unroll
            for (int nt = 0; nt < 4; ++nt)
#pragma unroll
                for (int reg = 0; reg < 4; ++reg)
                    __builtin_nontemporal_store(
                        silu_f(acc[p][nt][reg]),
                        &u_out[(m + reg) * 256 + bn0 + p * 64 + nt * 16 + l15]);
    } else if (bn0 < 512) {  // v region -> vtb (transposed) via padded-LDS overlay, per pair
#pragma unroll
        for (int p = 0; p < 2; ++p) {
            __syncthreads();  // waves done with As/Bs (p=0) or prior copy (p=1)
#pragma unroll
            for (int nt = 0; nt < 4; ++nt) {
                unsigned int p01 = f2bf2(silu_f(acc[p][nt][0]), silu_f(acc[p][nt][1]));
                unsigned int p23 = f2bf2(silu_f(acc[p][nt][2]), silu_f(acc[p][nt][3]));
                unsigned int pk2[2] = {p01, p23};
                *(uint2*)&T[nt * 16 + l15][w * 16 + quad * 4] = *(const uint2*)pk2;
            }
            __syncthreads();
            const int sr = tid >> 3, sc2 = (tid & 7) * 8;
#pragma unroll
            for (int i = 0; i < 2; ++i) {
                const int r = sr + i * 32;
                *(uint4*)(vtb + (size_t)(bn0 - 256 + p * 64 + r) * 6400 + bm + sc2) =
                    *(const uint4*)&T[r][sc2];
            }
        }
    } else {  // q/k region -> hb via row-major LDS overlay, coalesced uint4 stores, per pair
#pragma unroll
        for (int p = 0; p < 2; ++p) {
            __syncthreads();
#pragma unroll
            for (int nt = 0; nt < 4; ++nt) {
                unsigned int p01 = f2bf2(silu_f(acc[p][nt][0]), silu_f(acc[p][nt][1]));
                unsigned int p23 = f2bf2(silu_f(acc[p][nt][2]), silu_f(acc[p][nt][3]));
                T[w * 16 + quad * 4 + 0][nt * 16 + l15] = (unsigned short)p01;
                T[w * 16 + quad * 4 + 1][nt * 16 + l15] = (unsigned short)(p01 >> 16);
                T[w * 16 + quad * 4 + 2][nt * 16 + l15] = (unsigned short)p23;
                T[w * 16 + quad * 4 + 3][nt * 16 + l15] = (unsigned short)(p23 >> 16);
            }
            __syncthreads();
            const int sr = tid >> 3, sc2 = (tid & 7) * 8;
#pragma unroll
            for (int i = 0; i < 2; ++i) {
                const int r = sr + i * 32;
                *(uint4*)(hb + (size_t)(bm + r) * 768 + (bn0 - 256) + p * 64 + sc2) =
                    *(const uint4*)&T[r][sc2];
            }
        }
    }
}

// ---------------- K3: fused jagged SiLU attention, split-K (chunk=4), XCD->batch affinity,
//                  K/V staged via gload_lds into XOR-swizzled linear LDS (R17 pattern) --------
__global__ __launch_bounds__(256, 5) void k3_attn(const unsigned short* __restrict__ hb,
                                                  const unsigned short* __restrict__ vtb,
                                                  const int* __restrict__ ts,
                                                  const float* __restrict__ tsw,
                                                  const int* __restrict__ offs,
                                                  float* __restrict__ part) {
    // XCD-affinity decode (assumes xcd = linear_bid % 8; wrong assumption -> only mixes
    // batches, never wrong results). Work shares {3,2,1,2} XCDs for b={0,1,2,3}.
    // 32 slots per qt (8 chunks x 4 heads); per-XCD stream r = slot*kx + xi, qt
    // descending = LPT. Capacity: nqt*32 <= 512*kx holds for all b at these lengths.
    const int xcd = blockIdx.x & 7;
    const int slot = blockIdx.x >> 3;
    const int b = (xcd < 3) ? 0 : (xcd < 5) ? 1 : (xcd == 5) ? 2 : 3;
    const int xst = (b == 0) ? 0 : (b == 1) ? 3 : (b == 2) ? 5 : 6;
    const int kx = (b == 0) ? 3 : (b == 2) ? 1 : 2;
    const int r = slot * kx + (xcd - xst);
    const int off = offs[b];
    const int len = offs[b + 1] - off;
    const int nqt = len >> 6;
    const int qt_lpt = r >> 5;
    if (qt_lpt >= nqt) return;
    const int qt = nqt - 1 - qt_lpt;
    const int c = (r >> 2) & 7;
    const int hd = r & 3;
    if (c * 4 > qt) return;
    const int q0 = qt * 64;
    const int kt_lo = c * 4;
    const int kt_hi = min(qt, c * 4 + 3);

    __shared__ __align__(16) unsigned short QPs[64][72];  // Qs during init, Ps in loop (padded)
    __shared__ __align__(16) unsigned short Ks[4096];     // linear [64][64], XOR-swizzled
    __shared__ __align__(16) unsigned short Vt[4096];     // linear [64][64], XOR-swizzled
    __shared__ float tqf[64], tkf[64];
    __shared__ float tw[132];

    const int tid = threadIdx.x;
    const int lane = tid & 63;
    const int w = tid >> 6;
    const int l15 = lane & 15;
    const int quad = lane >> 4;
    const int sr = tid >> 3;
    const int sc = (tid & 7) * 8;

    // gload_lds staging geometry (same as k2): chunk j covers rows j*8..j*8+7;
    // lane l -> row (l>>3), col-group (l&7); pre-swizzled global col.
    const int srow = lane >> 3;
    const int scol = ((lane & 7) ^ srow) * 8;
    const int xA = (l15 & 7) << 3;  // read-side XOR

    if (tid < 129) tw[tid] = tsw[tid];
    if (tid < 64) tqf[tid] = (float)ts[b * 2048 + q0 + tid];
#pragma unroll
    for (int i = 0; i < 2; ++i)
        *(uint4*)&QPs[sr + i * 32][sc] =
            *(const uint4*)(hb + (off + q0 + sr + i * 32) * 768 + 256 + hd * 64 + sc);
    __syncthreads();

    const bf16x8 aQ0 = *(const bf16x8*)&QPs[w * 16 + l15][quad * 8];
    const bf16x8 aQ1 = *(const bf16x8*)&QPs[w * 16 + l15][32 + quad * 8];
    const f32x4 tq4 = *(const f32x4*)&tqf[w * 16 + quad * 4];
    const int nbase = q0 + w * 16 + quad * 4;

    // per-lane global staging bases (row offsets added per kt)
    const unsigned short* gK = hb + (size_t)(off + w * 8 + srow) * 768 + 512 + hd * 64 + scol;
    const unsigned short* gV = vtb + (size_t)(hd * 64 + w * 8 + srow) * 6400 + off + scol;

    f32x4 oacc[4] = {};

    for (int kt = kt_lo; kt <= kt_hi; ++kt) {
        const int m0 = kt * 64;
        __syncthreads();  // prior iteration's Ks/Vt/Ps reads done
#pragma unroll
        for (int i = 0; i < 2; ++i) {
            gload_lds16(gK + (size_t)(m0 + i * 32) * 768, Ks + (w + i * 4) * 512);
            gload_lds16(gV + (size_t)(i * 32) * 6400 + m0, Vt + (w + i * 4) * 512);
        }
        if (tid < 64) tkf[tid] = (float)ts[b * 2048 + m0 + tid];
        __syncthreads();  // vmcnt+lgkm drain -> tiles ready

        // S = Q @ K^T
        f32x4 s[4] = {};
#pragma unroll
        for (int nt = 0; nt < 4; ++nt) {
            bf16x8 b0 = *(const bf16x8*)&Ks[(nt * 16 + l15) * 64 + ((quad * 8) ^ xA)];
            bf16x8 b1 = *(const bf16x8*)&Ks[(nt * 16 + l15) * 64 + ((32 + quad * 8) ^ xA)];
            s[nt] = __builtin_amdgcn_mfma_f32_16x16x32_bf16(aQ0, b0, s[nt], 0, 0, 0);
            s[nt] = __builtin_amdgcn_mfma_f32_16x16x32_bf16(aQ1, b1, s[nt], 0, 0, 0);
        }

        // bias + silu/N + diagonal mask -> Ps (packed bf16 conversion)
        const bool diag = (kt == qt);
#pragma unroll
        for (int nt = 0; nt < 4; ++nt) {
            const int m = m0 + nt * 16 + l15;
            const float tk = tkf[nt * 16 + l15];
            float p[4];
#pragma unroll
            for (int reg = 0; reg < 4; ++reg) {
                const float delta = fabsf(tq4[reg] - tk);
                const int bucket = (int)(__log2f(1.0f + delta) * 0.6931471805599453f);
                float val = s[nt][reg] + tw[bucket];
                float pv = silu_over_2048(val);
                if (diag) pv = (m <= nbase + reg) ? pv : 0.0f;
                p[reg] = pv;
            }
            const unsigned int p01 = f2bf2(p[0], p[1]);
            const unsigned int p23 = f2bf2(p[2], p[3]);
            QPs[w * 16 + quad * 4 + 0][nt * 16 + l15] = (unsigned short)p01;
            QPs[w * 16 + quad * 4 + 1][nt * 16 + l15] = (unsigned short)(p01 >> 16);
            QPs[w * 16 + quad * 4 + 2][nt * 16 + l15] = (unsigned short)p23;
            QPs[w * 16 + quad * 4 + 3][nt * 16 + l15] = (unsigned short)(p23 >> 16);
        }
        // wave reads back only its own Ps rows -> no barrier needed

        const bf16x8 aP0 = *(const bf16x8*)&QPs[w * 16 + l15][quad * 8];
        const bf16x8 aP1 = *(const bf16x8*)&QPs[w * 16 + l15][32 + quad * 8];
#pragma unroll
        for (int nt = 0; nt < 4; ++nt) {
            bf16x8 v0 = *(const bf16x8*)&Vt[(nt * 16 + l15) * 64 + ((quad * 8) ^ xA)];
            bf16x8 v1 = *(const bf16x8*)&Vt[(nt * 16 + l15) * 64 + ((32 + quad * 8) ^ xA)];
            oacc[nt] = __builtin_amdgcn_mfma_f32_16x16x32_bf16(aP0, v0, oacc[nt], 0, 0, 0);
            oacc[nt] = __builtin_amdgcn_mfma_f32_16x16x32_bf16(aP1, v1, oacc[nt], 0, 0, 0);
        }
    }

    // part is streaming (read once by k4a): nontemporal, keep K/V resident in L2
    float* pc = part + (size_t)c * (6400 * 256);
#pragma unroll
    for (int nt = 0; nt < 4; ++nt)
#pragma unroll
        for (int reg = 0; reg < 4; ++reg)
            __builtin_nontemporal_store(
                oacc[nt][reg],
                &pc[(off + q0 + w * 16 + quad * 4 + reg) * 256 + hd * 64 + nt * 16 + l15]);
}

// ---------------- K4a: o_in = bf16(u * layernorm(sum_c part[c])); one wave per row ----------------
__global__ __launch_bounds__(256) void k4a_ln(const float* __restrict__ part,
                                              const float* __restrict__ u_in,
                                              const int* __restrict__ token_pos,
                                              unsigned short* __restrict__ o_in) {
    const int row = blockIdx.x * 4 + (threadIdx.x >> 6);
    const int lane = threadIdx.x & 63;
    const int qt = token_pos[row] >> 6;
    const int nch = (qt + 4) >> 2;  // ceil((qt+1)/4), max 8
    const size_t base = (size_t)row * 256 + lane * 4;
    f32x4 a = {0.0f, 0.0f, 0.0f, 0.0f};
    for (int cc = 0; cc < nch; ++cc) {
        const f32x4 p =
            __builtin_nontemporal_load((const f32x4*)(part + (size_t)cc * (6400 * 256) + base));
        a += p;
    }
    float s = a[0] + a[1] + a[2] + a[3];
    float ss = a[0] * a[0] + a[1] * a[1] + a[2] * a[2] + a[3] * a[3];
#pragma unroll
    for (int off = 32; off > 0; off >>= 1) {
        s += __shfl_down(s, off);
        ss += __shfl_down(ss, off);
    }
    s = __shfl(s, 0);
    ss = __shfl(ss, 0);
    const float mean = s * (1.0f / 256.0f);
    const float var = ss * (1.0f / 256.0f) - mean * mean;
    const float rstd = rsqrtf(var + 1e-6f);
    const f32x4 uu = __builtin_nontemporal_load((const f32x4*)(u_in + base));
    unsigned int pk[2];
    pk[0] = f2bf2(uu[0] * (a[0] - mean) * rstd, uu[1] * (a[1] - mean) * rstd);
    pk[1] = f2bf2(uu[2] * (a[2] - mean) * rstd, uu[3] * (a[3] - mean) * rstd);
    *(uint2*)(o_in + base) = *(const uint2*)pk;
}

// ---------------- K4b: out = o_in @ o_w^T + o_b + x via bf16 MFMA
//                  64x64 tile, gload_lds + XOR swizzle, XCD bm-chunk swizzle ----------------
__global__ __launch_bounds__(256, 4) void k4b_gemm2(const unsigned short* __restrict__ A,
                                                    const unsigned short* __restrict__ owb,
                                                    const float* __restrict__ ob,
                                                    const float* __restrict__ x,
                                                    float* __restrict__ out) {
    __shared__ __align__(16) unsigned short smem[8192];  // As[64][64] | Bs[64][64], 16 KB
    unsigned short* As = smem;
    unsigned short* Bs = smem + 4096;
    const int tid = threadIdx.x;
    const int lane = tid & 63;
    const int w = tid >> 6;
    const int l15 = lane & 15;
    const int quad = lane >> 4;
    // XCD bm-chunk swizzle: nwg=800 (%8==0 -> bijective)
    const int bid = blockIdx.x;
    const int kk_ = (bid & 7) * 100 + (bid >> 3);
    const int bm = (kk_ >> 3) * 64;
    const int bn = (kk_ & 7) * 64;

    const int srow = lane >> 3;
    const int scol = ((lane & 7) ^ srow) * 8;
    const unsigned short* gA = A + (size_t)(bm + w * 8 + srow) * 256 + scol;
    const unsigned short* gB = owb + (size_t)(bn + w * 8 + srow) * 256 + scol;

    const int xA = (l15 & 7) << 3;
    f32x4 acc[4] = {};
    for (int kc = 0; kc < 256; kc += 64) {
        __syncthreads();
#pragma unroll
        for (int i = 0; i < 2; ++i) {
            gload_lds16(gA + (size_t)(i * 32) * 256 + kc, As + (w + i * 4) * 512);
            gload_lds16(gB + (size_t)(i * 32) * 256 + kc, Bs + (w + i * 4) * 512);
        }
        __syncthreads();
        const bf16x8 a0 = *(const bf16x8*)&As[(w * 16 + l15) * 64 + ((quad * 8) ^ xA)];
        const bf16x8 a1 = *(const bf16x8*)&As[(w * 16 + l15) * 64 + ((32 + quad * 8) ^ xA)];
#pragma unroll
        for (int nt = 0; nt < 4; ++nt) {
            bf16x8 b0 = *(const bf16x8*)&Bs[(nt * 16 + l15) * 64 + ((quad * 8) ^ xA)];
            bf16x8 b1 = *(const bf16x8*)&Bs[(nt * 16 + l15) * 64 + ((32 + quad * 8) ^ xA)];
            acc[nt] = __builtin_amdgcn_mfma_f32_16x16x32_bf16(a0, b0, acc[nt], 0, 0, 0);
            acc[nt] = __builtin_amdgcn_mfma_f32_16x16x32_bf16(a1, b1, acc[nt], 0, 0, 0);
        }
    }
    const int m = bm + w * 16 + quad * 4;
#pragma unroll
    for (int nt = 0; nt < 4; ++nt) {
        const int d = bn + nt * 16 + l15;
        const float bias = ob[d];
#pragma unroll
        for (int reg = 0; reg < 4; ++reg)
            out[(m + reg) * 512 + d] = acc[nt][reg] + bias + x[(m + reg) * 512 + d];
    }
}

extern "C" void kernel_launch(void* const* d_in, const int* in_sizes, int n_in,
                              void* d_out, int out_size, void* d_ws, size_t ws_size,
                              hipStream_t stream) {
    const float* x = (const float*)d_in[0];       // [6400,512]
    const float* uvqk = (const float*)d_in[1];    // [512,1024]
    const float* ow = (const float*)d_in[2];      // [512,256]
    const float* ob = (const float*)d_in[3];      // [512]
    const float* tsw = (const float*)d_in[4];     // [129]
    const int* ts = (const int*)d_in[5];          // [4,2048]
    // d_in[6] invalid_attn_mask: pure tril -> implemented as m<=n, not read
    const int* offs = (const int*)d_in[7];        // [5]
    // d_in[8] token_batch (unused)
    const int* token_pos = (const int*)d_in[9];   // [6400]
    float* out = (float*)d_out;                   // [6400,512]

    float* ws = (float*)d_ws;
    float* u = ws;                                // 6400*256 f32
    float* part = u + 6400 * 256;                 // 8*6400*256 f32 (split-K partials)
    unsigned short* xnb = (unsigned short*)(part + 8 * 6400 * 256);  // 6400*512 bf16
    unsigned short* hb = xnb + 6400 * 512;        // 6400*768 bf16 (v cols unwritten)
    unsigned short* o_in = hb + 6400 * 768;       // 6400*256 bf16
    unsigned short* uvqkT = o_in + 6400 * 256;    // 1024*512 bf16
    unsigned short* owb = uvqkT + 1024 * 512;     // 512*256 bf16
    unsigned short* vtb = owb + 512 * 256;        // 256*6400 bf16
    // total ws use: ~86 MB

    k1_ln_prep<<<1792, 256, 0, stream>>>(x, xnb, uvqk, uvqkT, ow, owb);
    k2_gemm1<<<800, 256, 0, stream>>>(xnb, uvqkT, u, hb, vtb);
    k3_attn<<<4096, 256, 0, stream>>>(hb, vtb, ts, tsw, offs, part);
    k4a_ln<<<1600, 256, 0, stream>>>(part, u, token_pos, o_in);
    k4b_gemm2<<<800, 256, 0, stream>>>(o_in, owb, ob, x, out);
}